// Round 1
// baseline (1058.631 us; speedup 1.0000x reference)
//
#include <hip/hip_runtime.h>

namespace {
constexpr int kB = 64;
constexpr int kM = 4096;
constexpr int kN = 8192;
constexpr int kBM = kB * kM;   // 262144
constexpr int kBN = kB * kN;   // 524288
constexpr float W_PRIMAL = 0.1f;
constexpr float W_DUAL   = 0.1f;
constexpr float W_STAT   = 0.6f;
constexpr float W_COMP   = 0.2f;
}

// -------- scatter: Ax[row] += v * x[col];  AtLam[col] += v * lam[row] --------
__global__ void kkt_scatter(const float* __restrict__ a_vals,
                            const int*   __restrict__ a_rows,
                            const int*   __restrict__ a_cols,
                            const float* __restrict__ x_hat,
                            const float* __restrict__ lam_hat,
                            float* __restrict__ Ax,
                            float* __restrict__ AtLam,
                            int ngroups, int nnz)
{
    int g = blockIdx.x * blockDim.x + threadIdx.x;
    if (g < ngroups) {
        float4 v = reinterpret_cast<const float4*>(a_vals)[g];
        int4   r = reinterpret_cast<const int4*>(a_rows)[g];
        int4   c = reinterpret_cast<const int4*>(a_cols)[g];
        atomicAdd(&Ax[r.x], v.x * x_hat[c.x]);
        atomicAdd(&Ax[r.y], v.y * x_hat[c.y]);
        atomicAdd(&Ax[r.z], v.z * x_hat[c.z]);
        atomicAdd(&Ax[r.w], v.w * x_hat[c.w]);
        atomicAdd(&AtLam[c.x], v.x * lam_hat[r.x]);
        atomicAdd(&AtLam[c.y], v.y * lam_hat[r.y]);
        atomicAdd(&AtLam[c.z], v.z * lam_hat[r.z]);
        atomicAdd(&AtLam[c.w], v.w * lam_hat[r.w]);
    } else if (g == ngroups) {
        // scalar tail (nnz % 4 != 0); with nnz = 10,240,000 this never runs
        for (int i = ngroups * 4; i < nnz; ++i) {
            float v = a_vals[i];
            int   r = a_rows[i];
            int   c = a_cols[i];
            atomicAdd(&Ax[r], v * x_hat[c]);
            atomicAdd(&AtLam[c], v * lam_hat[r]);
        }
    }
}

// -------- reductions --------
__device__ __forceinline__ float block_reduce_sum(float v)
{
    __shared__ float smem[16];
    int lane = threadIdx.x & 63;
    int wave = threadIdx.x >> 6;
    #pragma unroll
    for (int off = 32; off > 0; off >>= 1)
        v += __shfl_down(v, off, 64);
    if (lane == 0) smem[wave] = v;
    __syncthreads();
    float s = 0.f;
    if (threadIdx.x == 0) {
        int nw = blockDim.x >> 6;
        for (int w = 0; w < nw; ++w) s += smem[w];
    }
    return s;  // valid only on thread 0
}

// M-side: primal part1 (relu(Ax-b)^2), dual part1 (relu(-lam)^2), comp part1 ((lam*(Ax-b))^2)
__global__ void kkt_reduce_m(const float* __restrict__ Ax,
                             const float* __restrict__ b_pad,
                             const float* __restrict__ lam_hat,
                             double* __restrict__ acc)
{
    float s = 0.f;
    int stride = gridDim.x * blockDim.x;
    for (int i = blockIdx.x * blockDim.x + threadIdx.x; i < kBM; i += stride) {
        float axmb = Ax[i] - b_pad[i];
        float l    = lam_hat[i];
        float rp   = fmaxf(axmb, 0.f);
        float rl   = fmaxf(-l, 0.f);
        float cm   = l * axmb;
        s += W_PRIMAL * rp * rp + W_DUAL * rl * rl + W_COMP * cm * cm;
    }
    s = block_reduce_sum(s);
    if (threadIdx.x == 0) {
        const double scale = 1.0 / ((double)(kM + kN) * (double)kB);
        atomicAdd(acc, (double)s * scale);
    }
}

// N-side: primal part2 (relu(-x)^2), stat (min(c+AtLam,0)^2, /N), comp part2 ((mu*x)^2)
// dual part2 (relu(-mu)^2) is identically zero since mu >= 0.
__global__ void kkt_reduce_n(const float* __restrict__ AtLam,
                             const float* __restrict__ c_pad,
                             const float* __restrict__ x_hat,
                             double* __restrict__ acc)
{
    float s1 = 0.f;  // weight 1/((M+N)*B)
    float s2 = 0.f;  // weight W_STAT/(N*B)
    int stride = gridDim.x * blockDim.x;
    for (int i = blockIdx.x * blockDim.x + threadIdx.x; i < kBN; i += stride) {
        float t  = AtLam[i] + c_pad[i];
        float mu = fmaxf(t, 0.f);
        float st = t - mu;           // == min(t, 0)
        float xx = x_hat[i];
        float rx = fmaxf(-xx, 0.f);
        float cm = mu * xx;
        s1 += W_PRIMAL * rx * rx + W_COMP * cm * cm;
        s2 += st * st;
    }
    // reduce both through one pass each
    float t1 = block_reduce_sum(s1);
    __syncthreads();  // smem reuse barrier
    float t2 = block_reduce_sum(s2);
    if (threadIdx.x == 0) {
        const double scale1 = 1.0 / ((double)(kM + kN) * (double)kB);
        const double scale2 = (double)W_STAT / ((double)kN * (double)kB);
        atomicAdd(acc, (double)t1 * scale1 + (double)t2 * scale2);
    }
}

__global__ void kkt_finalize(const double* __restrict__ acc, float* __restrict__ out)
{
    out[0] = (float)acc[0];
}

extern "C" void kernel_launch(void* const* d_in, const int* in_sizes, int n_in,
                              void* d_out, int out_size, void* d_ws, size_t ws_size,
                              hipStream_t stream)
{
    const float* x_hat   = (const float*)d_in[0];
    const float* lam_hat = (const float*)d_in[1];
    const float* a_vals  = (const float*)d_in[2];
    const int*   a_rows  = (const int*)d_in[3];
    const int*   a_cols  = (const int*)d_in[4];
    const float* b_pad   = (const float*)d_in[5];
    const float* c_pad   = (const float*)d_in[6];
    float* out = (float*)d_out;

    const int nnz = in_sizes[2];

    float*  Ax    = (float*)d_ws;
    float*  AtLam = Ax + kBM;
    double* acc   = (double*)((char*)d_ws + (size_t)(kBM + kBN) * sizeof(float));

    // zero Ax, AtLam and the accumulator (ws is re-poisoned to 0xAA every call)
    hipMemsetAsync(d_ws, 0, (size_t)(kBM + kBN) * sizeof(float) + sizeof(double), stream);

    const int ngroups = nnz / 4;
    const int tail    = (nnz & 3) ? 1 : 0;
    const int nthr    = ngroups + tail;
    kkt_scatter<<<dim3((nthr + 255) / 256), dim3(256), 0, stream>>>(
        a_vals, a_rows, a_cols, x_hat, lam_hat, Ax, AtLam, ngroups, nnz);

    kkt_reduce_m<<<dim3(256), dim3(256), 0, stream>>>(Ax, b_pad, lam_hat, acc);
    kkt_reduce_n<<<dim3(256), dim3(256), 0, stream>>>(AtLam, c_pad, x_hat, acc);
    kkt_finalize<<<1, 1, 0, stream>>>(acc, out);
}

// Round 2
// 244.563 us; speedup vs baseline: 4.3287x; 4.3287x over previous
//
#include <hip/hip_runtime.h>

namespace {
constexpr int kB = 64;
constexpr int kM = 4096;
constexpr int kN = 8192;
constexpr int kBM = kB * kM;   // 262144
constexpr int kBN = kB * kN;   // 524288
constexpr int kG  = 4;         // blocks per instance
constexpr float W_PRIMAL = 0.1f;
constexpr float W_DUAL   = 0.1f;
constexpr float W_STAT   = 0.6f;
constexpr float W_COMP   = 0.2f;
}

// -------- scatter with LDS privatization --------
// The COO stream is instance-sorted by construction (a_rows = item*M + r_local,
// item = repeat(arange(B), NNZ_PER)), so block (k, g) owns a contiguous chunk
// of instance k's nonzeros and accumulates into a private LDS copy of
// (Ax_k [16KB], AtLam_k [32KB]), then merges coalesced into global.
__global__ __launch_bounds__(512, 1) void kkt_scatter(
    const float* __restrict__ a_vals,
    const int*   __restrict__ a_rows,
    const int*   __restrict__ a_cols,
    const float* __restrict__ x_hat,
    const float* __restrict__ lam_hat,
    float* __restrict__ Ax,
    float* __restrict__ AtLam,
    int nnz_per, int nnz)
{
    __shared__ float s_ax[kM];   // 16 KB
    __shared__ float s_at[kN];   // 32 KB

    const int tid = threadIdx.x;
    const int bs  = blockDim.x;
    const int k   = blockIdx.x / kG;       // instance
    const int g   = blockIdx.x % kG;       // chunk within instance

    for (int j = tid; j < kM; j += bs) s_ax[j] = 0.f;
    for (int j = tid; j < kN; j += bs) s_at[j] = 0.f;
    __syncthreads();

    const int row_base = k * kM;
    const int col_base = k * kN;

    const int chunk  = nnz_per / kG;          // 40000
    const int base   = k * nnz_per + g * chunk;
    const int nq     = chunk >> 2;            // float4 groups
    const int qbase  = base >> 2;             // base % 4 == 0 here

    const float4* v4 = reinterpret_cast<const float4*>(a_vals);
    const int4*   r4 = reinterpret_cast<const int4*>(a_rows);
    const int4*   c4 = reinterpret_cast<const int4*>(a_cols);

    for (int q = tid; q < nq; q += bs) {
        float4 v = v4[qbase + q];
        int4   r = r4[qbase + q];
        int4   c = c4[qbase + q];
        atomicAdd(&s_ax[r.x - row_base], v.x * x_hat[c.x]);
        atomicAdd(&s_ax[r.y - row_base], v.y * x_hat[c.y]);
        atomicAdd(&s_ax[r.z - row_base], v.z * x_hat[c.z]);
        atomicAdd(&s_ax[r.w - row_base], v.w * x_hat[c.w]);
        atomicAdd(&s_at[c.x - col_base], v.x * lam_hat[r.x]);
        atomicAdd(&s_at[c.y - col_base], v.y * lam_hat[r.y]);
        atomicAdd(&s_at[c.z - col_base], v.z * lam_hat[r.z]);
        atomicAdd(&s_at[c.w - col_base], v.w * lam_hat[r.w]);
    }
    // scalar tail (never runs for chunk % 4 == 0)
    if (g == kG - 1 && tid == 0) {
        for (int i = base + (nq << 2); i < base + chunk; ++i) {
            float v = a_vals[i];
            atomicAdd(&s_ax[a_rows[i] - row_base], v * x_hat[a_cols[i]]);
            atomicAdd(&s_at[a_cols[i] - col_base], v * lam_hat[a_rows[i]]);
        }
    }
    __syncthreads();

    // coalesced merge: kG blocks collide per address, contiguous lanes
    for (int j = tid; j < kM; j += bs) atomicAdd(&Ax[row_base + j], s_ax[j]);
    for (int j = tid; j < kN; j += bs) atomicAdd(&AtLam[col_base + j], s_at[j]);
}

// -------- fused reduction over M-side and N-side --------
__device__ __forceinline__ float block_reduce_sum(float v)
{
    __shared__ float smem[16];
    int lane = threadIdx.x & 63;
    int wave = threadIdx.x >> 6;
    #pragma unroll
    for (int off = 32; off > 0; off >>= 1)
        v += __shfl_down(v, off, 64);
    if (lane == 0) smem[wave] = v;
    __syncthreads();
    float s = 0.f;
    if (threadIdx.x == 0) {
        int nw = blockDim.x >> 6;
        for (int w = 0; w < nw; ++w) s += smem[w];
    }
    return s;  // valid only on thread 0
}

__global__ void kkt_reduce(const float* __restrict__ Ax,
                           const float* __restrict__ b_pad,
                           const float* __restrict__ lam_hat,
                           const float* __restrict__ AtLam,
                           const float* __restrict__ c_pad,
                           const float* __restrict__ x_hat,
                           double* __restrict__ acc)
{
    const int mq = kBM / 4;          // 65536 float4 groups, M side
    const int nq = kBN / 4;          // 131072 float4 groups, N side
    float s1 = 0.f;                  // weight 1/((M+N)*B)
    float s2 = 0.f;                  // weight W_STAT/(N*B)
    const int stride = gridDim.x * blockDim.x;
    for (int idx = blockIdx.x * blockDim.x + threadIdx.x; idx < mq + nq; idx += stride) {
        if (idx < mq) {
            float4 ax = reinterpret_cast<const float4*>(Ax)[idx];
            float4 bb = reinterpret_cast<const float4*>(b_pad)[idx];
            float4 ll = reinterpret_cast<const float4*>(lam_hat)[idx];
            #pragma unroll
            for (int e = 0; e < 4; ++e) {
                float axmb = (&ax.x)[e] - (&bb.x)[e];
                float l    = (&ll.x)[e];
                float rp   = fmaxf(axmb, 0.f);
                float rl   = fmaxf(-l, 0.f);
                float cm   = l * axmb;
                s1 += W_PRIMAL * rp * rp + W_DUAL * rl * rl + W_COMP * cm * cm;
            }
        } else {
            int j = idx - mq;
            float4 at = reinterpret_cast<const float4*>(AtLam)[j];
            float4 cc = reinterpret_cast<const float4*>(c_pad)[j];
            float4 xx = reinterpret_cast<const float4*>(x_hat)[j];
            #pragma unroll
            for (int e = 0; e < 4; ++e) {
                float t  = (&at.x)[e] + (&cc.x)[e];
                float mu = fmaxf(t, 0.f);
                float st = t - mu;                 // min(t, 0); dual relu(-mu)^2 == 0
                float x  = (&xx.x)[e];
                float rx = fmaxf(-x, 0.f);
                float cm = mu * x;
                s1 += W_PRIMAL * rx * rx + W_COMP * cm * cm;
                s2 += st * st;
            }
        }
    }
    float t1 = block_reduce_sum(s1);
    __syncthreads();
    float t2 = block_reduce_sum(s2);
    if (threadIdx.x == 0) {
        const double scale1 = 1.0 / ((double)(kM + kN) * (double)kB);
        const double scale2 = (double)W_STAT / ((double)kN * (double)kB);
        atomicAdd(acc, (double)t1 * scale1 + (double)t2 * scale2);
    }
}

__global__ void kkt_finalize(const double* __restrict__ acc, float* __restrict__ out)
{
    out[0] = (float)acc[0];
}

extern "C" void kernel_launch(void* const* d_in, const int* in_sizes, int n_in,
                              void* d_out, int out_size, void* d_ws, size_t ws_size,
                              hipStream_t stream)
{
    const float* x_hat   = (const float*)d_in[0];
    const float* lam_hat = (const float*)d_in[1];
    const float* a_vals  = (const float*)d_in[2];
    const int*   a_rows  = (const int*)d_in[3];
    const int*   a_cols  = (const int*)d_in[4];
    const float* b_pad   = (const float*)d_in[5];
    const float* c_pad   = (const float*)d_in[6];
    float* out = (float*)d_out;

    const int nnz     = in_sizes[2];
    const int nnz_per = nnz / kB;

    float*  Ax    = (float*)d_ws;
    float*  AtLam = Ax + kBM;
    double* acc   = (double*)((char*)d_ws + (size_t)(kBM + kBN) * sizeof(float));

    hipMemsetAsync(d_ws, 0, (size_t)(kBM + kBN) * sizeof(float) + sizeof(double), stream);

    kkt_scatter<<<dim3(kB * kG), dim3(512), 0, stream>>>(
        a_vals, a_rows, a_cols, x_hat, lam_hat, Ax, AtLam, nnz_per, nnz);

    kkt_reduce<<<dim3(512), dim3(256), 0, stream>>>(
        Ax, b_pad, lam_hat, AtLam, c_pad, x_hat, acc);

    kkt_finalize<<<1, 1, 0, stream>>>(acc, out);
}

// Round 3
// 239.293 us; speedup vs baseline: 4.4240x; 1.0220x over previous
//
#include <hip/hip_runtime.h>

namespace {
constexpr int kB = 64;
constexpr int kM = 4096;
constexpr int kN = 8192;
constexpr int kBM = kB * kM;   // 262144
constexpr int kBN = kB * kN;   // 524288
constexpr int kG  = 4;         // chunks (blocks) per instance
constexpr float W_PRIMAL = 0.1f;
constexpr float W_DUAL   = 0.1f;
constexpr float W_STAT   = 0.6f;
constexpr float W_COMP   = 0.2f;
}

// -------- scatter, fully LDS-resident --------
// Block (k,g): load instance k's x slice (32KB) + lam slice (16KB) into LDS,
// accumulate its 40K-nnz chunk into private LDS accumulators (48KB), then
// store partials with plain coalesced stores into P_ax[g]/P_at[g].
// 96KB LDS -> 1 block/CU, 1024 threads = 16 waves/CU.
__global__ __launch_bounds__(1024, 4) void kkt_scatter(
    const float* __restrict__ a_vals,
    const int*   __restrict__ a_rows,
    const int*   __restrict__ a_cols,
    const float* __restrict__ x_hat,
    const float* __restrict__ lam_hat,
    float* __restrict__ P_ax,     // [kG][kBM]
    float* __restrict__ P_at,     // [kG][kBN]
    int nnz_per)
{
    __shared__ float s_x  [kN];  // 32 KB  instance x slice
    __shared__ float s_lam[kM];  // 16 KB  instance lam slice
    __shared__ float s_ax [kM];  // 16 KB  accumulator
    __shared__ float s_at [kN];  // 32 KB  accumulator

    const int tid = threadIdx.x;
    const int bs  = blockDim.x;
    const int k   = blockIdx.x / kG;
    const int g   = blockIdx.x % kG;
    const int row_base = k * kM;
    const int col_base = k * kN;

    // cooperative load of x/lam slices (coalesced float4) + zero accumulators
    {
        const float4* xg = reinterpret_cast<const float4*>(x_hat + col_base);
        const float4* lg = reinterpret_cast<const float4*>(lam_hat + row_base);
        float4* xs = reinterpret_cast<float4*>(s_x);
        float4* ls = reinterpret_cast<float4*>(s_lam);
        for (int j = tid; j < kN / 4; j += bs) xs[j] = xg[j];
        for (int j = tid; j < kM / 4; j += bs) ls[j] = lg[j];
        float4 z = {0.f, 0.f, 0.f, 0.f};
        float4* as = reinterpret_cast<float4*>(s_ax);
        float4* ts = reinterpret_cast<float4*>(s_at);
        for (int j = tid; j < kM / 4; j += bs) as[j] = z;
        for (int j = tid; j < kN / 4; j += bs) ts[j] = z;
    }
    __syncthreads();

    const int chunk = nnz_per / kG;        // 40000
    const int base  = k * nnz_per + g * chunk;
    const int nq    = chunk >> 2;
    const int qbase = base >> 2;           // base % 4 == 0 for this shape

    const float4* v4 = reinterpret_cast<const float4*>(a_vals);
    const int4*   r4 = reinterpret_cast<const int4*>(a_rows);
    const int4*   c4 = reinterpret_cast<const int4*>(a_cols);

    for (int q = tid; q < nq; q += bs) {
        float4 v = v4[qbase + q];
        int4   r = r4[qbase + q];
        int4   c = c4[qbase + q];
        int rl0 = r.x - row_base, rl1 = r.y - row_base,
            rl2 = r.z - row_base, rl3 = r.w - row_base;
        int cl0 = c.x - col_base, cl1 = c.y - col_base,
            cl2 = c.z - col_base, cl3 = c.w - col_base;
        float x0 = s_x[cl0], x1 = s_x[cl1], x2 = s_x[cl2], x3 = s_x[cl3];
        float l0 = s_lam[rl0], l1 = s_lam[rl1], l2 = s_lam[rl2], l3 = s_lam[rl3];
        atomicAdd(&s_ax[rl0], v.x * x0);
        atomicAdd(&s_ax[rl1], v.y * x1);
        atomicAdd(&s_ax[rl2], v.z * x2);
        atomicAdd(&s_ax[rl3], v.w * x3);
        atomicAdd(&s_at[cl0], v.x * l0);
        atomicAdd(&s_at[cl1], v.y * l1);
        atomicAdd(&s_at[cl2], v.z * l2);
        atomicAdd(&s_at[cl3], v.w * l3);
    }
    // scalar tail (never runs when chunk % 4 == 0)
    if ((chunk & 3) && g == kG - 1 && tid == 0) {
        for (int i = base + (nq << 2); i < base + chunk; ++i) {
            float v = a_vals[i];
            atomicAdd(&s_ax[a_rows[i] - row_base], v * s_x[a_cols[i] - col_base]);
            atomicAdd(&s_at[a_cols[i] - col_base], v * s_lam[a_rows[i] - row_base]);
        }
    }
    __syncthreads();

    // plain coalesced stores of partials (no global atomics, no memset needed)
    {
        float4* pa = reinterpret_cast<float4*>(P_ax + (size_t)g * kBM + row_base);
        float4* pt = reinterpret_cast<float4*>(P_at + (size_t)g * kBN + col_base);
        const float4* as = reinterpret_cast<const float4*>(s_ax);
        const float4* ts = reinterpret_cast<const float4*>(s_at);
        for (int j = tid; j < kM / 4; j += bs) pa[j] = as[j];
        for (int j = tid; j < kN / 4; j += bs) pt[j] = ts[j];
    }
}

// -------- fused reduction (sums kG partials inline) --------
__device__ __forceinline__ float block_reduce_sum(float v)
{
    __shared__ float smem[16];
    int lane = threadIdx.x & 63;
    int wave = threadIdx.x >> 6;
    #pragma unroll
    for (int off = 32; off > 0; off >>= 1)
        v += __shfl_down(v, off, 64);
    if (lane == 0) smem[wave] = v;
    __syncthreads();
    float s = 0.f;
    if (threadIdx.x == 0) {
        int nw = blockDim.x >> 6;
        for (int w = 0; w < nw; ++w) s += smem[w];
    }
    return s;  // valid only on thread 0
}

__global__ void kkt_reduce(const float* __restrict__ P_ax,
                           const float* __restrict__ P_at,
                           const float* __restrict__ b_pad,
                           const float* __restrict__ lam_hat,
                           const float* __restrict__ c_pad,
                           const float* __restrict__ x_hat,
                           float* __restrict__ acc)
{
    const int mq = kBM / 4;
    const int nq = kBN / 4;
    float s1 = 0.f;                  // weight 1/((M+N)*B)
    float s2 = 0.f;                  // weight W_STAT/(N*B)
    const int stride = gridDim.x * blockDim.x;
    for (int idx = blockIdx.x * blockDim.x + threadIdx.x; idx < mq + nq; idx += stride) {
        if (idx < mq) {
            float4 ax = reinterpret_cast<const float4*>(P_ax)[idx];
            #pragma unroll
            for (int g = 1; g < kG; ++g) {
                float4 p = reinterpret_cast<const float4*>(P_ax + (size_t)g * kBM)[idx];
                ax.x += p.x; ax.y += p.y; ax.z += p.z; ax.w += p.w;
            }
            float4 bb = reinterpret_cast<const float4*>(b_pad)[idx];
            float4 ll = reinterpret_cast<const float4*>(lam_hat)[idx];
            #pragma unroll
            for (int e = 0; e < 4; ++e) {
                float axmb = (&ax.x)[e] - (&bb.x)[e];
                float l    = (&ll.x)[e];
                float rp   = fmaxf(axmb, 0.f);
                float rl   = fmaxf(-l, 0.f);
                float cm   = l * axmb;
                s1 += W_PRIMAL * rp * rp + W_DUAL * rl * rl + W_COMP * cm * cm;
            }
        } else {
            int j = idx - mq;
            float4 at = reinterpret_cast<const float4*>(P_at)[j];
            #pragma unroll
            for (int g = 1; g < kG; ++g) {
                float4 p = reinterpret_cast<const float4*>(P_at + (size_t)g * kBN)[j];
                at.x += p.x; at.y += p.y; at.z += p.z; at.w += p.w;
            }
            float4 cc = reinterpret_cast<const float4*>(c_pad)[j];
            float4 xx = reinterpret_cast<const float4*>(x_hat)[j];
            #pragma unroll
            for (int e = 0; e < 4; ++e) {
                float t  = (&at.x)[e] + (&cc.x)[e];
                float mu = fmaxf(t, 0.f);
                float st = t - mu;                 // min(t,0); dual relu(-mu)^2 == 0
                float x  = (&xx.x)[e];
                float rx = fmaxf(-x, 0.f);
                float cm = mu * x;
                s1 += W_PRIMAL * rx * rx + W_COMP * cm * cm;
                s2 += st * st;
            }
        }
    }
    float t1 = block_reduce_sum(s1);
    __syncthreads();
    float t2 = block_reduce_sum(s2);
    if (threadIdx.x == 0) {
        const float scale1 = 1.0f / ((float)(kM + kN) * (float)kB);
        const float scale2 = W_STAT / ((float)kN * (float)kB);
        atomicAdd(acc, t1 * scale1 + t2 * scale2);
    }
}

// zero the scalar accumulator (ws is poisoned 0xAA before every call)
__global__ void kkt_zero(float* __restrict__ acc) { acc[0] = 0.f; }

__global__ void kkt_finalize(const float* __restrict__ acc, float* __restrict__ out)
{
    out[0] = acc[0];
}

extern "C" void kernel_launch(void* const* d_in, const int* in_sizes, int n_in,
                              void* d_out, int out_size, void* d_ws, size_t ws_size,
                              hipStream_t stream)
{
    const float* x_hat   = (const float*)d_in[0];
    const float* lam_hat = (const float*)d_in[1];
    const float* a_vals  = (const float*)d_in[2];
    const int*   a_rows  = (const int*)d_in[3];
    const int*   a_cols  = (const int*)d_in[4];
    const float* b_pad   = (const float*)d_in[5];
    const float* c_pad   = (const float*)d_in[6];
    float* out = (float*)d_out;

    const int nnz     = in_sizes[2];
    const int nnz_per = nnz / kB;

    float* P_ax = (float*)d_ws;                         // kG*kBM floats (4 MB)
    float* P_at = P_ax + (size_t)kG * kBM;              // kG*kBN floats (8 MB)
    float* acc  = P_at + (size_t)kG * kBN;              // 1 float

    kkt_zero<<<1, 1, 0, stream>>>(acc);

    kkt_scatter<<<dim3(kB * kG), dim3(1024), 0, stream>>>(
        a_vals, a_rows, a_cols, x_hat, lam_hat, P_ax, P_at, nnz_per);

    kkt_reduce<<<dim3(512), dim3(256), 0, stream>>>(
        P_ax, P_at, b_pad, lam_hat, c_pad, x_hat, acc);

    kkt_finalize<<<1, 1, 0, stream>>>(acc, out);
}

// Round 4
// 233.398 us; speedup vs baseline: 4.5357x; 1.0253x over previous
//
#include <hip/hip_runtime.h>

namespace {
constexpr int kB = 64;
constexpr int kM = 4096;
constexpr int kN = 8192;
constexpr int kBM = kB * kM;   // 262144
constexpr int kBN = kB * kN;   // 524288
constexpr int kG  = 4;         // chunks (blocks) per instance
constexpr int kRBlocks = 1024; // reduce grid size (must match finalize)
constexpr float W_PRIMAL = 0.1f;
constexpr float W_DUAL   = 0.1f;
constexpr float W_STAT   = 0.6f;
constexpr float W_COMP   = 0.2f;
}

// -------- scatter, fully LDS-resident, NATIVE fp32 LDS atomics --------
// fp32 atomicAdd lowers to a CAS retry loop on HIP (both global and LDS) —
// that was the 97%-stall bottleneck of rounds 1-3. unsafeAtomicAdd emits
// native ds_add_f32 (fire-and-forget, no retry loop).
__global__ __launch_bounds__(1024, 4) void kkt_scatter(
    const float* __restrict__ a_vals,
    const int*   __restrict__ a_rows,
    const int*   __restrict__ a_cols,
    const float* __restrict__ x_hat,
    const float* __restrict__ lam_hat,
    float* __restrict__ P_ax,     // [kG][kBM]
    float* __restrict__ P_at,     // [kG][kBN]
    int nnz_per)
{
    __shared__ float s_x  [kN];  // 32 KB  instance x slice
    __shared__ float s_lam[kM];  // 16 KB  instance lam slice
    __shared__ float s_ax [kM];  // 16 KB  accumulator
    __shared__ float s_at [kN];  // 32 KB  accumulator

    const int tid = threadIdx.x;
    const int bs  = blockDim.x;
    const int k   = blockIdx.x / kG;
    const int g   = blockIdx.x % kG;
    const int row_base = k * kM;
    const int col_base = k * kN;

    // cooperative load of x/lam slices (coalesced float4) + zero accumulators
    {
        const float4* xg = reinterpret_cast<const float4*>(x_hat + col_base);
        const float4* lg = reinterpret_cast<const float4*>(lam_hat + row_base);
        float4* xs = reinterpret_cast<float4*>(s_x);
        float4* ls = reinterpret_cast<float4*>(s_lam);
        for (int j = tid; j < kN / 4; j += bs) xs[j] = xg[j];
        for (int j = tid; j < kM / 4; j += bs) ls[j] = lg[j];
        float4 z = {0.f, 0.f, 0.f, 0.f};
        float4* as = reinterpret_cast<float4*>(s_ax);
        float4* ts = reinterpret_cast<float4*>(s_at);
        for (int j = tid; j < kM / 4; j += bs) as[j] = z;
        for (int j = tid; j < kN / 4; j += bs) ts[j] = z;
    }
    __syncthreads();

    const int chunk = nnz_per / kG;        // 40000
    const int base  = k * nnz_per + g * chunk;
    const int nq    = chunk >> 2;
    const int qbase = base >> 2;           // base % 4 == 0 for this shape

    const float4* v4 = reinterpret_cast<const float4*>(a_vals);
    const int4*   r4 = reinterpret_cast<const int4*>(a_rows);
    const int4*   c4 = reinterpret_cast<const int4*>(a_cols);

    for (int q = tid; q < nq; q += bs) {
        float4 v = v4[qbase + q];
        int4   r = r4[qbase + q];
        int4   c = c4[qbase + q];
        int rl0 = r.x - row_base, rl1 = r.y - row_base,
            rl2 = r.z - row_base, rl3 = r.w - row_base;
        int cl0 = c.x - col_base, cl1 = c.y - col_base,
            cl2 = c.z - col_base, cl3 = c.w - col_base;
        float x0 = s_x[cl0], x1 = s_x[cl1], x2 = s_x[cl2], x3 = s_x[cl3];
        float l0 = s_lam[rl0], l1 = s_lam[rl1], l2 = s_lam[rl2], l3 = s_lam[rl3];
        unsafeAtomicAdd(&s_ax[rl0], v.x * x0);
        unsafeAtomicAdd(&s_ax[rl1], v.y * x1);
        unsafeAtomicAdd(&s_ax[rl2], v.z * x2);
        unsafeAtomicAdd(&s_ax[rl3], v.w * x3);
        unsafeAtomicAdd(&s_at[cl0], v.x * l0);
        unsafeAtomicAdd(&s_at[cl1], v.y * l1);
        unsafeAtomicAdd(&s_at[cl2], v.z * l2);
        unsafeAtomicAdd(&s_at[cl3], v.w * l3);
    }
    // scalar tail (never runs when chunk % 4 == 0)
    if ((chunk & 3) && g == kG - 1 && tid == 0) {
        for (int i = base + (nq << 2); i < base + chunk; ++i) {
            float v = a_vals[i];
            unsafeAtomicAdd(&s_ax[a_rows[i] - row_base], v * s_x[a_cols[i] - col_base]);
            unsafeAtomicAdd(&s_at[a_cols[i] - col_base], v * s_lam[a_rows[i] - row_base]);
        }
    }
    __syncthreads();

    // plain coalesced stores of partials (no global atomics, no memset needed)
    {
        float4* pa = reinterpret_cast<float4*>(P_ax + (size_t)g * kBM + row_base);
        float4* pt = reinterpret_cast<float4*>(P_at + (size_t)g * kBN + col_base);
        const float4* as = reinterpret_cast<const float4*>(s_ax);
        const float4* ts = reinterpret_cast<const float4*>(s_at);
        for (int j = tid; j < kM / 4; j += bs) pa[j] = as[j];
        for (int j = tid; j < kN / 4; j += bs) pt[j] = ts[j];
    }
}

// -------- fused reduction: per-block partial via plain store (NO contended atomic) --------
__device__ __forceinline__ float block_reduce_sum(float v)
{
    __shared__ float smem[16];
    int lane = threadIdx.x & 63;
    int wave = threadIdx.x >> 6;
    #pragma unroll
    for (int off = 32; off > 0; off >>= 1)
        v += __shfl_down(v, off, 64);
    if (lane == 0) smem[wave] = v;
    __syncthreads();
    float s = 0.f;
    if (threadIdx.x == 0) {
        int nw = blockDim.x >> 6;
        for (int w = 0; w < nw; ++w) s += smem[w];
    }
    return s;  // valid only on thread 0
}

__global__ void kkt_reduce(const float* __restrict__ P_ax,
                           const float* __restrict__ P_at,
                           const float* __restrict__ b_pad,
                           const float* __restrict__ lam_hat,
                           const float* __restrict__ c_pad,
                           const float* __restrict__ x_hat,
                           float* __restrict__ partials)
{
    const int mq = kBM / 4;
    const int nq = kBN / 4;
    float s1 = 0.f;                  // weight 1/((M+N)*B)
    float s2 = 0.f;                  // weight W_STAT/(N*B)
    const int stride = gridDim.x * blockDim.x;
    for (int idx = blockIdx.x * blockDim.x + threadIdx.x; idx < mq + nq; idx += stride) {
        if (idx < mq) {
            float4 ax = reinterpret_cast<const float4*>(P_ax)[idx];
            #pragma unroll
            for (int g = 1; g < kG; ++g) {
                float4 p = reinterpret_cast<const float4*>(P_ax + (size_t)g * kBM)[idx];
                ax.x += p.x; ax.y += p.y; ax.z += p.z; ax.w += p.w;
            }
            float4 bb = reinterpret_cast<const float4*>(b_pad)[idx];
            float4 ll = reinterpret_cast<const float4*>(lam_hat)[idx];
            #pragma unroll
            for (int e = 0; e < 4; ++e) {
                float axmb = (&ax.x)[e] - (&bb.x)[e];
                float l    = (&ll.x)[e];
                float rp   = fmaxf(axmb, 0.f);
                float rl   = fmaxf(-l, 0.f);
                float cm   = l * axmb;
                s1 += W_PRIMAL * rp * rp + W_DUAL * rl * rl + W_COMP * cm * cm;
            }
        } else {
            int j = idx - mq;
            float4 at = reinterpret_cast<const float4*>(P_at)[j];
            #pragma unroll
            for (int g = 1; g < kG; ++g) {
                float4 p = reinterpret_cast<const float4*>(P_at + (size_t)g * kBN)[j];
                at.x += p.x; at.y += p.y; at.z += p.z; at.w += p.w;
            }
            float4 cc = reinterpret_cast<const float4*>(c_pad)[j];
            float4 xx = reinterpret_cast<const float4*>(x_hat)[j];
            #pragma unroll
            for (int e = 0; e < 4; ++e) {
                float t  = (&at.x)[e] + (&cc.x)[e];
                float mu = fmaxf(t, 0.f);
                float st = t - mu;                 // min(t,0); dual relu(-mu)^2 == 0
                float x  = (&xx.x)[e];
                float rx = fmaxf(-x, 0.f);
                float cm = mu * x;
                s1 += W_PRIMAL * rx * rx + W_COMP * cm * cm;
                s2 += st * st;
            }
        }
    }
    const float scale1 = 1.0f / ((float)(kM + kN) * (float)kB);
    const float scale2 = W_STAT / ((float)kN * (float)kB);
    float t = block_reduce_sum(s1 * scale1 + s2 * scale2);
    if (threadIdx.x == 0) partials[blockIdx.x] = t;
}

// single block sums the kRBlocks partials
__global__ __launch_bounds__(1024) void kkt_finalize(const float* __restrict__ partials,
                                                     float* __restrict__ out)
{
    float v = partials[threadIdx.x];           // blockDim.x == kRBlocks
    float t = block_reduce_sum(v);
    if (threadIdx.x == 0) out[0] = t;
}

extern "C" void kernel_launch(void* const* d_in, const int* in_sizes, int n_in,
                              void* d_out, int out_size, void* d_ws, size_t ws_size,
                              hipStream_t stream)
{
    const float* x_hat   = (const float*)d_in[0];
    const float* lam_hat = (const float*)d_in[1];
    const float* a_vals  = (const float*)d_in[2];
    const int*   a_rows  = (const int*)d_in[3];
    const int*   a_cols  = (const int*)d_in[4];
    const float* b_pad   = (const float*)d_in[5];
    const float* c_pad   = (const float*)d_in[6];
    float* out = (float*)d_out;

    const int nnz     = in_sizes[2];
    const int nnz_per = nnz / kB;

    float* P_ax     = (float*)d_ws;                     // kG*kBM floats (4 MB)
    float* P_at     = P_ax + (size_t)kG * kBM;          // kG*kBN floats (8 MB)
    float* partials = P_at + (size_t)kG * kBN;          // kRBlocks floats

    kkt_scatter<<<dim3(kB * kG), dim3(1024), 0, stream>>>(
        a_vals, a_rows, a_cols, x_hat, lam_hat, P_ax, P_at, nnz_per);

    kkt_reduce<<<dim3(kRBlocks), dim3(256), 0, stream>>>(
        P_ax, P_at, b_pad, lam_hat, c_pad, x_hat, partials);

    kkt_finalize<<<1, dim3(kRBlocks), 0, stream>>>(partials, out);
}